// Round 6
// baseline (286.783 us; speedup 1.0000x reference)
//
#include <hip/hip_runtime.h>
#include <hip/hip_bf16.h>
#include <math.h>

#define POST 128
#define NI 129            // T+1
#define NJK 4225          // 65*65
#define KPAD 4288         // 67*64
#define NTOT 16512        // 129*128
#define KBLKS 134         // KPAD/32 (k-blocks of 32)
#define MBLKS 32          // 512/16
#define KSTEPS 67         // KPAD/64
#define KSPLIT 34         // first block's share of KSTEPS

typedef __attribute__((ext_vector_type(8))) short bf16x8;
typedef __attribute__((ext_vector_type(4))) float f32x4;
typedef __attribute__((ext_vector_type(4))) unsigned int u32x4;

__device__ __forceinline__ unsigned short f2bf(float f){
    unsigned u = __builtin_bit_cast(unsigned, f);
    unsigned r = (u + 0x7FFFu + ((u >> 16) & 1u)) >> 16;   // RNE
    return (unsigned short)r;
}
__device__ __forceinline__ unsigned pack2(float a, float b){
    return (unsigned)f2bf(a) | ((unsigned)f2bf(b) << 16);
}

// ---------------- K1: build VA (bf16) in MFMA A-fragment granule order --------
// granule (kblk, mblk): 64 lanes x 16B; element (l,j): m=mblk*16+(l&15),
// k = kblk*32 + (l>>4)*8 + j. Zero-padded past NJK.
__global__ void build_af(const float* __restrict__ audio,
                         const float* __restrict__ video,
                         uint4* __restrict__ af)
{
    int gid = blockIdx.x * 256 + threadIdx.x;
    if (gid >= KBLKS * MBLKS * 64) return;
    int lane = gid & 63;
    int mblk = (gid >> 6) & 31;
    int kblk = gid >> 11;
    int m  = mblk * 16 + (lane & 15);
    int k0 = kblk * 32 + (lane >> 4) * 8;
    float vals[8];
#pragma unroll
    for (int j = 0; j < 8; ++j){
        int k = k0 + j;
        float p = 0.f;
        if (k < NJK){
            int jj = k / 65;
            int kk = k - jj * 65;
            float a = (kk == 0) ? 1.f : audio[m * 64 + kk - 1];
            float v = (jj == 0) ? 1.f : video[m * 64 + jj - 1];
            p = a * v;
        }
        vals[j] = p;
    }
    uint4 o;
    o.x = pack2(vals[0], vals[1]);
    o.y = pack2(vals[2], vals[3]);
    o.z = pack2(vals[4], vals[5]);
    o.w = pack2(vals[6], vals[7]);
    af[gid] = o;
}

// ---------------- K2: fused Z = VA @ bf16(W1'), split-K x2 --------------------
// 128x128 tile, BK=64, grid 1032 = 4 mt x 129 nt x 2 kb, 4 waves (2x2 of 64x64).
// B: fp32 global -> RNE cvt in reg -> ds_write_b128 [n][k] XOR-swizzled, dbuf.
// A: direct per-wave global loads from af granules (granule == fragment), no LDS.
__global__ __launch_bounds__(256, 3) void fusion_gemm(
    const float* __restrict__ W1,
    const uint4* __restrict__ af,
    float* __restrict__ Z0,
    float* __restrict__ Z1)
{
    __shared__ __align__(16) char lds[32768];   // B only: [0,16K) buf0 | [16K,32K) buf1

    // XCD swizzle (nwg=1032 = 8*129): 8 blocks of one nt stay on one XCD
    int orig = blockIdx.x;
    int xcd  = orig & 7;
    int w    = xcd * 129 + (orig >> 3);
    int nt  = w >> 3;          // 0..128
    int sub = w & 7;
    int mt  = sub & 3;         // 0..3
    int kb  = sub >> 2;        // 0..1

    int ks0 = kb ? KSPLIT : 0;
    int ks1 = kb ? KSTEPS : KSPLIT;

    int t    = threadIdx.x;
    int lane = t & 63;
    int wv   = t >> 6;
    int wm   = wv >> 1, wn = wv & 1;

    f32x4 acc[4][4] = {};

    const float* wpanel = W1 + (size_t)nt * (NJK * 128);

    // B staging: thread covers n in {nb, nb+64}, k rows kg*8..kg*8+7 (+c*32)
    int nb = t & 63;
    int kg = t >> 6;          // wave-uniform

    float vB[2][2][8];        // [c][half][j]

#define BLOAD(ks_)                                                          \
    do {                                                                    \
        if ((ks_) == KSTEPS - 1) {                                          \
            _Pragma("unroll")                                               \
            for (int c = 0; c < 2; ++c){                                    \
                int kr0 = (ks_) * 64 + c * 32 + kg * 8;                     \
                _Pragma("unroll")                                           \
                for (int j = 0; j < 8; ++j){                                \
                    int kr = kr0 + j; kr = kr < 4224 ? kr : 4224;           \
                    vB[c][0][j] = wpanel[(size_t)kr * 128 + nb];            \
                    vB[c][1][j] = wpanel[(size_t)kr * 128 + nb + 64];       \
                }                                                           \
            }                                                               \
        } else {                                                            \
            _Pragma("unroll")                                               \
            for (int c = 0; c < 2; ++c){                                    \
                const float* wr = wpanel + (size_t)((ks_) * 64 + c * 32 + kg * 8) * 128 + nb; \
                _Pragma("unroll")                                           \
                for (int j = 0; j < 8; ++j){                                \
                    vB[c][0][j] = wr[j * 128];                              \
                    vB[c][1][j] = wr[j * 128 + 64];                         \
                }                                                           \
            }                                                               \
        }                                                                   \
    } while (0)

#define BWRITE(buf_)                                                        \
    do {                                                                    \
        char* dstb_ = lds + (buf_) * 16384;                                 \
        _Pragma("unroll")                                                   \
        for (int c = 0; c < 2; ++c){                                        \
            _Pragma("unroll")                                               \
            for (int h = 0; h < 2; ++h){                                    \
                int n_ = nb + h * 64;                                       \
                u32x4 u_;                                                   \
                u_.x = pack2(vB[c][h][0], vB[c][h][1]);                     \
                u_.y = pack2(vB[c][h][2], vB[c][h][3]);                     \
                u_.z = pack2(vB[c][h][4], vB[c][h][5]);                     \
                u_.w = pack2(vB[c][h][6], vB[c][h][7]);                     \
                int byte_ = (n_ * 128 + c * 64 + kg * 16) ^ ((n_ & 7) << 4);\
                *(u32x4*)(dstb_ + byte_) = u_;                              \
            }                                                               \
        }                                                                   \
    } while (0)

    // prologue
    BLOAD(ks0);
    BWRITE(0);
    __syncthreads();

    for (int ks = ks0; ks < ks1; ++ks){
        int it = ks - ks0;
        if (ks + 1 < ks1){
            BLOAD(ks + 1);
            __builtin_amdgcn_sched_barrier(0);   // pin: loads issue before compute
        }

        // ---- compute from B buf [it&1]; A direct from global (granule==fragment)
        {
            const char* sb = lds + (it & 1) * 16384;
#pragma unroll
            for (int s = 0; s < 2; ++s){
                const uint4* ag = af + (size_t)((2 * ks + s) * 32 + mt * 8 + wm * 4) * 64 + lane;
                bf16x8 a[4], b[4];
#pragma unroll
                for (int f = 0; f < 4; ++f)
                    a[f] = __builtin_bit_cast(bf16x8, ag[f * 64]);
#pragma unroll
                for (int g = 0; g < 4; ++g){
                    int nr = wn * 64 + g * 16 + (lane & 15);
                    int byte = (nr * 128 + s * 64 + (lane >> 4) * 16) ^ ((nr & 7) << 4);
                    b[g] = *(const bf16x8*)(sb + byte);
                }
#pragma unroll
                for (int f = 0; f < 4; ++f)
#pragma unroll
                    for (int g = 0; g < 4; ++g)
                        acc[f][g] = __builtin_amdgcn_mfma_f32_16x16x32_bf16(a[f], b[g], acc[f][g], 0, 0, 0);
            }
        }

        if (ks + 1 < ks1)
            BWRITE((it + 1) & 1);
        __syncthreads();
    }

    // epilogue: D layout col=lane&15, row=(lane>>4)*4+reg
    float* Zp = kb ? Z1 : Z0;
    int row0 = mt * 128 + wm * 64 + (lane >> 4) * 4;
    int col0 = nt * 128 + wn * 64 + (lane & 15);
#pragma unroll
    for (int f = 0; f < 4; ++f)
#pragma unroll
        for (int g = 0; g < 4; ++g)
#pragma unroll
            for (int r = 0; r < 4; ++r)
                Zp[(size_t)(row0 + f * 16 + r) * NTOT + col0 + g * 16] = acc[f][g][r];
}

// ---------------- K3: y1 = relu(b1 + sum_i t1_i * (Z0+Z1)); y2; sigmoid head ---
__global__ void tail_mlp(const float* __restrict__ Z0,
                         const float* __restrict__ Z1,
                         const float* __restrict__ text,
                         const float* __restrict__ b1,
                         const float* __restrict__ W2,
                         const float* __restrict__ b2,
                         const float* __restrict__ W3,
                         const float* __restrict__ b3,
                         float* __restrict__ out)
{
    int b   = blockIdx.x;     // 512
    int tid = threadIdx.x;    // 128
    __shared__ float t1s[NI];
    __shared__ float y1s[POST];
    __shared__ float red[2];

    t1s[tid + 1] = text[b * 128 + tid];
    if (tid == 0) t1s[0] = 1.f;
    __syncthreads();

    const float* z0 = Z0 + (size_t)b * NTOT;
    const float* z1 = Z1 + (size_t)b * NTOT;
    float acc = 0.f;
    for (int i = 0; i < NI; ++i)
        acc = fmaf(t1s[i], z0[i * 128 + tid] + z1[i * 128 + tid], acc);
    acc += b1[tid];
    float y1 = fmaxf(acc, 0.f);
    y1s[tid] = y1;
    __syncthreads();

    float a2 = b2[tid];
    for (int q = 0; q < 128; ++q)
        a2 = fmaf(y1s[q], W2[q * 128 + tid], a2);
    float y2 = fmaxf(a2, 0.f);

    float part = y2 * W3[tid];
#pragma unroll
    for (int off = 32; off > 0; off >>= 1)
        part += __shfl_down(part, off);
    if ((tid & 63) == 0) red[tid >> 6] = part;
    __syncthreads();
    if (tid == 0){
        float z = red[0] + red[1] + b3[0];
        out[b] = 6.f / (1.f + expf(-z)) - 3.f;
    }
}

extern "C" void kernel_launch(void* const* d_in, const int* in_sizes, int n_in,
                              void* d_out, int out_size, void* d_ws, size_t ws_size,
                              hipStream_t stream)
{
    const float* audio = (const float*)d_in[0];
    const float* video = (const float*)d_in[1];
    const float* text  = (const float*)d_in[2];
    const float* W1    = (const float*)d_in[3];
    const float* b1    = (const float*)d_in[4];
    const float* W2    = (const float*)d_in[5];
    const float* b2    = (const float*)d_in[6];
    const float* W3    = (const float*)d_in[7];
    const float* b3    = (const float*)d_in[8];
    float* out = (float*)d_out;

    char* ws = (char*)d_ws;
    uint4* af = (uint4*)ws;                       // 4,390,912 B
    float* Z0 = (float*)(ws + (8u  << 20));       // 33,816,576 B
    float* Z1 = (float*)(ws + (48u << 20));       // 33,816,576 B

    int af_granules = KBLKS * MBLKS * 64;         // 274432 threads
    build_af<<<(af_granules + 255) / 256, 256, 0, stream>>>(audio, video, af);
    fusion_gemm<<<1032, 256, 0, stream>>>(W1, af, Z0, Z1);
    tail_mlp<<<512, 128, 0, stream>>>(Z0, Z1, text, b1, W2, b2, W3, b3, out);
}